// Round 1
// baseline (1361.742 us; speedup 1.0000x reference)
//
#include <hip/hip_runtime.h>
#include <math.h>

#define N_NODES 10000
#define N_EDGES 160000
#define HIDDEN 128
#define NUM_RBF 32
#define LATENT 64
#define N_GRAPHS 128
#define CUTOFF 5.0f
#define EPS 1e-8f

__device__ __forceinline__ float silu(float v) {
    return v / (1.0f + expf(-v));
}

__global__ void zero_kernel(float* __restrict__ p, int n) {
    int i = blockIdx.x * blockDim.x + threadIdx.x;
    if (i < n) p[i] = 0.0f;
}

// per-edge: r, dirn, rbf
__global__ void geom_kernel(const float* __restrict__ pos, const int* __restrict__ ei,
                            float* __restrict__ rbf, float* __restrict__ dirn) {
    int e = blockIdx.x * blockDim.x + threadIdx.x;
    if (e >= N_EDGES) return;
    int s = ei[e];
    int t = ei[N_EDGES + e];
    float dx = pos[t * 3 + 0] - pos[s * 3 + 0];
    float dy = pos[t * 3 + 1] - pos[s * 3 + 1];
    float dz = pos[t * 3 + 2] - pos[s * 3 + 2];
    float r = sqrtf(dx * dx + dy * dy + dz * dz + EPS);
    float inv = 1.0f / r;
    dirn[e * 3 + 0] = dx * inv;
    dirn[e * 3 + 1] = dy * inv;
    dirn[e * 3 + 2] = dz * inv;

    float e5 = expf(-CUTOFF);
    float span = 1.0f - e5;
    float b = (2.0f / NUM_RBF) * span;
    float beta = 1.0f / (b * b);
    float cut = (r < CUTOFF) ? 0.5f * (cosf((float)M_PI * r / CUTOFF) + 1.0f) : 0.0f;
    float er = expf(-r);
#pragma unroll
    for (int k = 0; k < NUM_RBF; k++) {
        float mean = e5 + span * ((float)k / (NUM_RBF - 1));
        float d = er - mean;
        rbf[e * NUM_RBF + k] = cut * expf(-beta * d * d);
    }
}

__global__ void init_x_kernel(const int* __restrict__ z, const float* __restrict__ embed,
                              float* __restrict__ x) {
    int i = blockIdx.x * blockDim.x + threadIdx.x;
    if (i < N_NODES * HIDDEN) {
        int n = i >> 7;
        int h = i & 127;
        x[i] = embed[z[n] * HIDDEN + h];
    }
}

// per node: vmix[n] = vec[n] (3x128) @ Wv (128x128)
__global__ void vmix_kernel(const float* __restrict__ vec, const float* __restrict__ Wv,
                            float* __restrict__ vmix) {
    __shared__ float sv[3 * HIDDEN];
    int n = blockIdx.x;
    int h = threadIdx.x;
    sv[h] = vec[n * 384 + h];
    sv[h + 128] = vec[n * 384 + 128 + h];
    sv[h + 256] = vec[n * 384 + 256 + h];
    __syncthreads();
#pragma unroll
    for (int c = 0; c < 3; c++) {
        float acc = 0.0f;
        for (int j = 0; j < HIDDEN; j++) acc += sv[c * HIDDEN + j] * Wv[j * HIDDEN + h];
        vmix[n * 384 + c * HIDDEN + h] = acc;
    }
}

// per edge, block=128: filt -> phi -> scatter dx, vmsg
__global__ void edge_kernel(const int* __restrict__ ei, const float* __restrict__ x,
                            const float* __restrict__ rbf, const float* __restrict__ dirn,
                            const float* __restrict__ vmix, const float* __restrict__ Wrbf,
                            const float* __restrict__ W1, float* __restrict__ dxb,
                            float* __restrict__ vec) {
    __shared__ float s_rbf[NUM_RBF];
    __shared__ float s_tmp[HIDDEN];
    int e = blockIdx.x;
    int h = threadIdx.x;
    int src = ei[e];
    int dst = ei[N_EDGES + e];
    if (h < NUM_RBF) s_rbf[h] = rbf[e * NUM_RBF + h];
    __syncthreads();

    float filt = 0.0f;
#pragma unroll
    for (int k = 0; k < NUM_RBF; k++) filt += s_rbf[k] * Wrbf[k * HIDDEN + h];

    s_tmp[h] = x[src * HIDDEN + h] * filt;
    __syncthreads();

    float acc = 0.0f;
    for (int j = 0; j < HIDDEN; j++) acc += s_tmp[j] * W1[j * HIDDEN + h];
    float phi = silu(acc);

    atomicAdd(&dxb[dst * HIDDEN + h], phi);

    float d0 = dirn[e * 3 + 0];
    float d1 = dirn[e * 3 + 1];
    float d2 = dirn[e * 3 + 2];
    atomicAdd(&vec[dst * 384 + 0 * HIDDEN + h], vmix[src * 384 + 0 * HIDDEN + h] * filt + phi * d0);
    atomicAdd(&vec[dst * 384 + 1 * HIDDEN + h], vmix[src * 384 + 1 * HIDDEN + h] * filt + phi * d1);
    atomicAdd(&vec[dst * 384 + 2 * HIDDEN + h], vmix[src * 384 + 2 * HIDDEN + h] * filt + phi * d2);
}

// per node: x += dx @ Wo
__global__ void node_update_kernel(const float* __restrict__ dxb, const float* __restrict__ Wo,
                                   float* __restrict__ x) {
    __shared__ float s_dx[HIDDEN];
    int n = blockIdx.x;
    int h = threadIdx.x;
    s_dx[h] = dxb[n * HIDDEN + h];
    __syncthreads();
    float acc = 0.0f;
    for (int j = 0; j < HIDDEN; j++) acc += s_dx[j] * Wo[j * HIDDEN + h];
    x[n * HIDDEN + h] += acc;
}

// per node: v2 = vec @ Wvec2; vnorm; a = silu([x,vnorm]@W_a + b_a); out = a@W_b + b_b; pool
__global__ void final_node_kernel(const float* __restrict__ x, const float* __restrict__ vec,
                                  const float* __restrict__ Wvec2, const float* __restrict__ W_a,
                                  const float* __restrict__ b_a, const float* __restrict__ W_b,
                                  const float* __restrict__ b_b, const int* __restrict__ batch,
                                  float* __restrict__ pooled) {
    __shared__ float sv[3 * HIDDEN];
    __shared__ float sx[HIDDEN];
    __shared__ float svn[HIDDEN];
    __shared__ float sa[HIDDEN];
    int n = blockIdx.x;
    int h = threadIdx.x;
    sv[h] = vec[n * 384 + h];
    sv[h + 128] = vec[n * 384 + 128 + h];
    sv[h + 256] = vec[n * 384 + 256 + h];
    sx[h] = x[n * HIDDEN + h];
    __syncthreads();

    float v2a = 0.0f, v2b = 0.0f, v2c = 0.0f;
    for (int j = 0; j < HIDDEN; j++) {
        float w = Wvec2[j * HIDDEN + h];
        v2a += sv[j] * w;
        v2b += sv[HIDDEN + j] * w;
        v2c += sv[2 * HIDDEN + j] * w;
    }
    svn[h] = sqrtf(v2a * v2a + v2b * v2b + v2c * v2c + EPS);
    __syncthreads();

    float acc = b_a[h];
    for (int j = 0; j < HIDDEN; j++) acc += sx[j] * W_a[j * HIDDEN + h];
    for (int j = 0; j < HIDDEN; j++) acc += svn[j] * W_a[(HIDDEN + j) * HIDDEN + h];
    sa[h] = silu(acc);
    __syncthreads();

    if (h < LATENT + 1) {
        float o = b_b[h];
        for (int j = 0; j < HIDDEN; j++) o += sa[j] * W_b[j * (LATENT + 1) + h];
        atomicAdd(&pooled[batch[n] * (LATENT + 1) + h], o);
    }
}

__global__ void finalize_kernel(const float* __restrict__ pooled, float* __restrict__ out) {
    int i = blockIdx.x * blockDim.x + threadIdx.x;
    if (i >= N_GRAPHS * (LATENT + 1)) return;
    int g = i / (LATENT + 1);
    int k = i % (LATENT + 1);
    float v = pooled[i];
    if (k < LATENT) {
        out[g * LATENT + k] = v;
    } else {
        v = fminf(fmaxf(v, -10.0f), 2.0f);
        out[N_GRAPHS * LATENT + g] = v;
    }
}

extern "C" void kernel_launch(void* const* d_in, const int* in_sizes, int n_in,
                              void* d_out, int out_size, void* d_ws, size_t ws_size,
                              hipStream_t stream) {
    const int* z = (const int*)d_in[0];
    const float* pos = (const float*)d_in[1];
    const int* batch = (const int*)d_in[2];
    const int* ei = (const int*)d_in[3];
    const float* embed = (const float*)d_in[4];
    const float* W_rbf = (const float*)d_in[5];
    const float* W1 = (const float*)d_in[6];
    const float* Wo = (const float*)d_in[7];
    const float* Wv = (const float*)d_in[8];
    // d_in[9] = Wvec1, unused by reference
    const float* Wvec2 = (const float*)d_in[10];
    const float* W_a = (const float*)d_in[11];
    const float* b_a = (const float*)d_in[12];
    const float* W_b = (const float*)d_in[13];
    const float* b_b = (const float*)d_in[14];
    float* out = (float*)d_out;

    float* ws = (float*)d_ws;
    float* rbf = ws;                              // E*32
    float* dirn = rbf + (size_t)N_EDGES * 32;     // E*3
    float* x = dirn + (size_t)N_EDGES * 3;        // N*128
    float* vec = x + (size_t)N_NODES * 128;       // N*384
    float* vmix = vec + (size_t)N_NODES * 384;    // N*384
    float* dxb = vmix + (size_t)N_NODES * 384;    // N*128
    float* pooled = dxb + (size_t)N_NODES * 128;  // 128*65

    geom_kernel<<<(N_EDGES + 255) / 256, 256, 0, stream>>>(pos, ei, rbf, dirn);
    init_x_kernel<<<(N_NODES * HIDDEN + 255) / 256, 256, 0, stream>>>(z, embed, x);
    zero_kernel<<<(N_NODES * 384 + 255) / 256, 256, 0, stream>>>(vec, N_NODES * 384);

    for (int l = 0; l < 2; l++) {
        vmix_kernel<<<N_NODES, 128, 0, stream>>>(vec, Wv + (size_t)l * HIDDEN * HIDDEN, vmix);
        zero_kernel<<<(N_NODES * HIDDEN + 255) / 256, 256, 0, stream>>>(dxb, N_NODES * HIDDEN);
        edge_kernel<<<N_EDGES, 128, 0, stream>>>(ei, x, rbf, dirn, vmix,
                                                 W_rbf + (size_t)l * NUM_RBF * HIDDEN,
                                                 W1 + (size_t)l * HIDDEN * HIDDEN, dxb, vec);
        node_update_kernel<<<N_NODES, 128, 0, stream>>>(dxb, Wo + (size_t)l * HIDDEN * HIDDEN, x);
    }

    zero_kernel<<<(N_GRAPHS * (LATENT + 1) + 255) / 256, 256, 0, stream>>>(pooled,
                                                                          N_GRAPHS * (LATENT + 1));
    final_node_kernel<<<N_NODES, 128, 0, stream>>>(x, vec, Wvec2, W_a, b_a, W_b, b_b, batch,
                                                   pooled);
    finalize_kernel<<<(N_GRAPHS * (LATENT + 1) + 255) / 256, 256, 0, stream>>>(pooled, out);
}

// Round 2
// 809.354 us; speedup vs baseline: 1.6825x; 1.6825x over previous
//
#include <hip/hip_runtime.h>
#include <math.h>

#define N_NODES 10000
#define N_EDGES 160000
#define HIDDEN 128
#define NUM_RBF 32
#define LATENT 64
#define N_GRAPHS 128
#define CUTOFF 5.0f
#define EPS 1e-8f

__device__ __forceinline__ float silu(float v) { return v / (1.0f + expf(-v)); }

__global__ void zero_f_kernel(float* __restrict__ p, int n) {
    int i = blockIdx.x * blockDim.x + threadIdx.x;
    if (i < n) p[i] = 0.0f;
}
__global__ void zero_i_kernel(int* __restrict__ p, int n) {
    int i = blockIdx.x * blockDim.x + threadIdx.x;
    if (i < n) p[i] = 0;
}

// per-edge geometry: rbf (E x 32), dirn (E x 3)
__global__ void geom_kernel(const float* __restrict__ pos, const int* __restrict__ ei,
                            float* __restrict__ rbf, float* __restrict__ dirn) {
    int e = blockIdx.x * blockDim.x + threadIdx.x;
    if (e >= N_EDGES) return;
    int s = ei[e];
    int t = ei[N_EDGES + e];
    float dx = pos[t * 3 + 0] - pos[s * 3 + 0];
    float dy = pos[t * 3 + 1] - pos[s * 3 + 1];
    float dz = pos[t * 3 + 2] - pos[s * 3 + 2];
    float r = sqrtf(dx * dx + dy * dy + dz * dz + EPS);
    float inv = 1.0f / r;
    dirn[e * 3 + 0] = dx * inv;
    dirn[e * 3 + 1] = dy * inv;
    dirn[e * 3 + 2] = dz * inv;

    float e5 = expf(-CUTOFF);
    float span = 1.0f - e5;
    float b = (2.0f / NUM_RBF) * span;
    float beta = 1.0f / (b * b);
    float cut = (r < CUTOFF) ? 0.5f * (cosf((float)M_PI * r / CUTOFF) + 1.0f) : 0.0f;
    float er = expf(-r);
#pragma unroll
    for (int k = 0; k < NUM_RBF; k++) {
        float mean = e5 + span * ((float)k / (NUM_RBF - 1));
        float d = er - mean;
        rbf[e * NUM_RBF + k] = cut * expf(-beta * d * d);
    }
}

__global__ void hist_kernel(const int* __restrict__ dst, int* __restrict__ deg) {
    int e = blockIdx.x * blockDim.x + threadIdx.x;
    if (e < N_EDGES) atomicAdd(&deg[dst[e]], 1);
}

// single block, 1024 threads: exclusive prefix over deg[10000] -> rowptr[10001], cursor
__global__ void prefix_kernel(const int* __restrict__ deg, int* __restrict__ rowptr,
                              int* __restrict__ cursor) {
    __shared__ int part[1024];
    const int ITEMS = 10;  // 1024*10 >= 10000
    int t = threadIdx.x;
    int base = t * ITEMS;
    int local[ITEMS];
    int s = 0;
#pragma unroll
    for (int j = 0; j < ITEMS; j++) {
        int idx = base + j;
        int v = (idx < N_NODES) ? deg[idx] : 0;
        local[j] = s;
        s += v;
    }
    part[t] = s;
    __syncthreads();
    for (int off = 1; off < 1024; off <<= 1) {
        int v = (t >= off) ? part[t - off] : 0;
        __syncthreads();
        part[t] += v;
        __syncthreads();
    }
    int base_sum = (t > 0) ? part[t - 1] : 0;
#pragma unroll
    for (int j = 0; j < ITEMS; j++) {
        int idx = base + j;
        if (idx < N_NODES) {
            rowptr[idx] = base_sum + local[j];
            cursor[idx] = base_sum + local[j];
        }
    }
    if (t == 1023) rowptr[N_NODES] = part[1023];
}

__global__ void scatter_kernel(const int* __restrict__ dst, int* __restrict__ cursor,
                               int* __restrict__ eperm) {
    int e = blockIdx.x * blockDim.x + threadIdx.x;
    if (e < N_EDGES) {
        int p = atomicAdd(&cursor[dst[e]], 1);
        eperm[p] = e;
    }
}

__global__ void init_x_kernel(const int* __restrict__ z, const float* __restrict__ embed,
                              float* __restrict__ x) {
    int i = blockIdx.x * blockDim.x + threadIdx.x;
    if (i < N_NODES * HIDDEN) {
        int n = i >> 7;
        int h = i & 127;
        x[i] = embed[z[n] * HIDDEN + h];
    }
}

// ---------------- generic tiled GEMM: C = epi(A[MxK] @ W[Kx128]) ----------------
// EPI bits: 1=bias, 2=add Cin, 4=silu
template <int K, int EPI>
__global__ __launch_bounds__(256) void gemm_nn(const float* __restrict__ A,
                                               const float* __restrict__ W,
                                               const float* __restrict__ bias,
                                               const float* __restrict__ Cin,
                                               float* __restrict__ C, int M) {
    constexpr int STR = K + 4;
    __shared__ float As[64 * STR];
    int tid = threadIdx.x;
    int rg = tid >> 5;  // 0..7
    int cg = tid & 31;  // 0..31
    int row0 = blockIdx.x * 64;

    for (int idx = tid; idx < 64 * (K / 4); idx += 256) {
        int r = idx / (K / 4);
        int k4 = idx % (K / 4);
        float4 v = make_float4(0.f, 0.f, 0.f, 0.f);
        if (row0 + r < M) v = *(const float4*)(A + (size_t)(row0 + r) * K + k4 * 4);
        *(float4*)(As + r * STR + k4 * 4) = v;
    }
    __syncthreads();

    float acc[8][4];
#pragma unroll
    for (int i = 0; i < 8; i++)
#pragma unroll
        for (int j = 0; j < 4; j++) acc[i][j] = 0.f;

    const float* Wp = W + cg * 4;
#pragma unroll 4
    for (int k4 = 0; k4 < K / 4; k4++) {
        float4 w0 = *(const float4*)(Wp + (k4 * 4 + 0) * 128);
        float4 w1 = *(const float4*)(Wp + (k4 * 4 + 1) * 128);
        float4 w2 = *(const float4*)(Wp + (k4 * 4 + 2) * 128);
        float4 w3 = *(const float4*)(Wp + (k4 * 4 + 3) * 128);
#pragma unroll
        for (int i = 0; i < 8; i++) {
            float4 av = *(const float4*)(As + (rg * 8 + i) * STR + k4 * 4);
            acc[i][0] += av.x * w0.x + av.y * w1.x + av.z * w2.x + av.w * w3.x;
            acc[i][1] += av.x * w0.y + av.y * w1.y + av.z * w2.y + av.w * w3.y;
            acc[i][2] += av.x * w0.z + av.y * w1.z + av.z * w2.z + av.w * w3.z;
            acc[i][3] += av.x * w0.w + av.y * w1.w + av.z * w2.w + av.w * w3.w;
        }
    }

    float4 bv = make_float4(0.f, 0.f, 0.f, 0.f);
    if (EPI & 1) bv = *(const float4*)(bias + cg * 4);
#pragma unroll
    for (int i = 0; i < 8; i++) {
        int r = row0 + rg * 8 + i;
        if (r < M) {
            float4 o;
            o.x = acc[i][0] + bv.x;
            o.y = acc[i][1] + bv.y;
            o.z = acc[i][2] + bv.z;
            o.w = acc[i][3] + bv.w;
            if (EPI & 2) {
                float4 ci = *(const float4*)(Cin + (size_t)r * 128 + cg * 4);
                o.x += ci.x; o.y += ci.y; o.z += ci.z; o.w += ci.w;
            }
            if (EPI & 4) {
                o.x = silu(o.x); o.y = silu(o.y); o.z = silu(o.z); o.w = silu(o.w);
            }
            *(float4*)(C + (size_t)r * 128 + cg * 4) = o;
        }
    }
}

// ------------- fused edge GEMM: filt = rbf@Wrbf; t = filt*x[src] (LDS); phi = silu(t@W1) -------------
__global__ __launch_bounds__(256) void edge_gemm(const float* __restrict__ rbf,
                                                 const float* __restrict__ Wrbf,
                                                 const float* __restrict__ x,
                                                 const int* __restrict__ srcs,
                                                 const float* __restrict__ W1,
                                                 float* __restrict__ filt_out,
                                                 float* __restrict__ phi_out) {
    __shared__ float Rs[64 * 36];
    __shared__ float Ts[64 * 132];
    __shared__ int s_src[64];
    int tid = threadIdx.x;
    int rg = tid >> 5;
    int cg = tid & 31;
    int row0 = blockIdx.x * 64;

    for (int idx = tid; idx < 64 * 8; idx += 256) {
        int r = idx / 8;
        int k4 = idx % 8;
        float4 v = *(const float4*)(rbf + (size_t)(row0 + r) * 32 + k4 * 4);
        *(float4*)(Rs + r * 36 + k4 * 4) = v;
    }
    if (tid < 64) s_src[tid] = srcs[row0 + tid];
    __syncthreads();

    float acc[8][4];
#pragma unroll
    for (int i = 0; i < 8; i++)
#pragma unroll
        for (int j = 0; j < 4; j++) acc[i][j] = 0.f;

    const float* Wp = Wrbf + cg * 4;
#pragma unroll
    for (int k4 = 0; k4 < 8; k4++) {
        float4 w0 = *(const float4*)(Wp + (k4 * 4 + 0) * 128);
        float4 w1 = *(const float4*)(Wp + (k4 * 4 + 1) * 128);
        float4 w2 = *(const float4*)(Wp + (k4 * 4 + 2) * 128);
        float4 w3 = *(const float4*)(Wp + (k4 * 4 + 3) * 128);
#pragma unroll
        for (int i = 0; i < 8; i++) {
            float4 av = *(const float4*)(Rs + (rg * 8 + i) * 36 + k4 * 4);
            acc[i][0] += av.x * w0.x + av.y * w1.x + av.z * w2.x + av.w * w3.x;
            acc[i][1] += av.x * w0.y + av.y * w1.y + av.z * w2.y + av.w * w3.y;
            acc[i][2] += av.x * w0.z + av.y * w1.z + av.z * w2.z + av.w * w3.z;
            acc[i][3] += av.x * w0.w + av.y * w1.w + av.z * w2.w + av.w * w3.w;
        }
    }

    // epilogue: write filt, build t in LDS
#pragma unroll
    for (int i = 0; i < 8; i++) {
        int r = rg * 8 + i;
        int s = s_src[r];
        float4 xv = *(const float4*)(x + (size_t)s * 128 + cg * 4);
        float4 f;
        f.x = acc[i][0]; f.y = acc[i][1]; f.z = acc[i][2]; f.w = acc[i][3];
        *(float4*)(filt_out + (size_t)(row0 + r) * 128 + cg * 4) = f;
        float4 t;
        t.x = f.x * xv.x; t.y = f.y * xv.y; t.z = f.z * xv.z; t.w = f.w * xv.w;
        *(float4*)(Ts + r * 132 + cg * 4) = t;
    }
    __syncthreads();

    // phi = silu(t @ W1)
    float acc2[8][4];
#pragma unroll
    for (int i = 0; i < 8; i++)
#pragma unroll
        for (int j = 0; j < 4; j++) acc2[i][j] = 0.f;

    const float* W1p = W1 + cg * 4;
#pragma unroll 4
    for (int k4 = 0; k4 < 32; k4++) {
        float4 w0 = *(const float4*)(W1p + (k4 * 4 + 0) * 128);
        float4 w1 = *(const float4*)(W1p + (k4 * 4 + 1) * 128);
        float4 w2 = *(const float4*)(W1p + (k4 * 4 + 2) * 128);
        float4 w3 = *(const float4*)(W1p + (k4 * 4 + 3) * 128);
#pragma unroll
        for (int i = 0; i < 8; i++) {
            float4 av = *(const float4*)(Ts + (rg * 8 + i) * 132 + k4 * 4);
            acc2[i][0] += av.x * w0.x + av.y * w1.x + av.z * w2.x + av.w * w3.x;
            acc2[i][1] += av.x * w0.y + av.y * w1.y + av.z * w2.y + av.w * w3.y;
            acc2[i][2] += av.x * w0.z + av.y * w1.z + av.z * w2.z + av.w * w3.z;
            acc2[i][3] += av.x * w0.w + av.y * w1.w + av.z * w2.w + av.w * w3.w;
        }
    }
#pragma unroll
    for (int i = 0; i < 8; i++) {
        int r = row0 + rg * 8 + i;
        float4 o;
        o.x = silu(acc2[i][0]); o.y = silu(acc2[i][1]);
        o.z = silu(acc2[i][2]); o.w = silu(acc2[i][3]);
        *(float4*)(phi_out + (size_t)r * 128 + cg * 4) = o;
    }
}

// ------------- CSR gather per dst node: dx and vec accumulation, no atomics -------------
__global__ void gather_kernel(const int* __restrict__ rowptr, const int* __restrict__ eperm,
                              const int* __restrict__ srcs, const float* __restrict__ filt,
                              const float* __restrict__ phi, const float* __restrict__ dirn,
                              const float* __restrict__ vmix, float* __restrict__ dxb,
                              float* __restrict__ vec) {
    int n = blockIdx.x;
    int h = threadIdx.x;
    int beg = rowptr[n];
    int end = rowptr[n + 1];
    float dx = 0.f, v0 = 0.f, v1 = 0.f, v2 = 0.f;
    for (int i = beg; i < end; i++) {
        int e = eperm[i];
        int s = srcs[e];
        float f = filt[(size_t)e * 128 + h];
        float p = phi[(size_t)e * 128 + h];
        float d0 = dirn[e * 3 + 0];
        float d1 = dirn[e * 3 + 1];
        float d2 = dirn[e * 3 + 2];
        dx += p;
        v0 += vmix[(size_t)(s * 3 + 0) * 128 + h] * f + p * d0;
        v1 += vmix[(size_t)(s * 3 + 1) * 128 + h] * f + p * d1;
        v2 += vmix[(size_t)(s * 3 + 2) * 128 + h] * f + p * d2;
    }
    dxb[(size_t)n * 128 + h] = dx;
    vec[(size_t)(n * 3 + 0) * 128 + h] += v0;
    vec[(size_t)(n * 3 + 1) * 128 + h] += v1;
    vec[(size_t)(n * 3 + 2) * 128 + h] += v2;
}

// vnorm[n][h] = sqrt(sum_c v2[n][c][h]^2 + EPS)
__global__ void vnorm_kernel(const float* __restrict__ v2, float* __restrict__ vnorm) {
    int i = blockIdx.x * blockDim.x + threadIdx.x;
    if (i >= N_NODES * HIDDEN) return;
    int n = i >> 7;
    int h = i & 127;
    float a = v2[(size_t)(n * 3 + 0) * 128 + h];
    float b = v2[(size_t)(n * 3 + 1) * 128 + h];
    float c = v2[(size_t)(n * 3 + 2) * 128 + h];
    vnorm[i] = sqrtf(a * a + b * b + c * c + EPS);
}

// per node: out = a @ W_b + b_b, atomically pooled by batch
__global__ void out_pool_kernel(const float* __restrict__ a, const float* __restrict__ W_b,
                                const float* __restrict__ b_b, const int* __restrict__ batch,
                                float* __restrict__ pooled) {
    __shared__ float sa[HIDDEN];
    int n = blockIdx.x;
    int h = threadIdx.x;
    sa[h] = a[(size_t)n * 128 + h];
    __syncthreads();
    if (h < LATENT + 1) {
        float o = b_b[h];
        for (int j = 0; j < HIDDEN; j++) o += sa[j] * W_b[j * (LATENT + 1) + h];
        atomicAdd(&pooled[batch[n] * (LATENT + 1) + h], o);
    }
}

__global__ void finalize_kernel(const float* __restrict__ pooled, float* __restrict__ out) {
    int i = blockIdx.x * blockDim.x + threadIdx.x;
    if (i >= N_GRAPHS * (LATENT + 1)) return;
    int g = i / (LATENT + 1);
    int k = i % (LATENT + 1);
    float v = pooled[i];
    if (k < LATENT) {
        out[g * LATENT + k] = v;
    } else {
        v = fminf(fmaxf(v, -10.0f), 2.0f);
        out[N_GRAPHS * LATENT + g] = v;
    }
}

extern "C" void kernel_launch(void* const* d_in, const int* in_sizes, int n_in,
                              void* d_out, int out_size, void* d_ws, size_t ws_size,
                              hipStream_t stream) {
    const int* z = (const int*)d_in[0];
    const float* pos = (const float*)d_in[1];
    const int* batch = (const int*)d_in[2];
    const int* ei = (const int*)d_in[3];
    const float* embed = (const float*)d_in[4];
    const float* W_rbf = (const float*)d_in[5];
    const float* W1 = (const float*)d_in[6];
    const float* Wo = (const float*)d_in[7];
    const float* Wv = (const float*)d_in[8];
    const float* Wvec2 = (const float*)d_in[10];
    const float* W_a = (const float*)d_in[11];
    const float* b_a = (const float*)d_in[12];
    const float* W_b = (const float*)d_in[13];
    const float* b_b = (const float*)d_in[14];
    float* out = (float*)d_out;

    const int* srcs = ei;
    const int* dsts = ei + N_EDGES;

    float* ws = (float*)d_ws;
    float* rbf = ws;                                    // E*32
    float* dirn = rbf + (size_t)N_EDGES * 32;           // E*3
    float* filt = dirn + (size_t)N_EDGES * 3;           // E*128
    float* phi = filt + (size_t)N_EDGES * 128;          // E*128
    float* x = phi + (size_t)N_EDGES * 128;             // N*128
    float* vec = x + (size_t)N_NODES * 128;             // N*384
    float* vmix = vec + (size_t)N_NODES * 384;          // N*384 (later reused as v2)
    float* dxb = vmix + (size_t)N_NODES * 384;          // N*128 (later reused as vnorm)
    float* tmpa = dxb + (size_t)N_NODES * 128;          // N*128
    float* abuf = tmpa + (size_t)N_NODES * 128;         // N*128
    float* pooled = abuf + (size_t)N_NODES * 128;       // 128*65
    int* ibase = (int*)(pooled + N_GRAPHS * (LATENT + 1));
    int* deg = ibase;              // N
    int* rowptr = deg + N_NODES;   // N+1
    int* cursor = rowptr + N_NODES + 1;  // N
    int* eperm = cursor + N_NODES;       // E

    // geometry + CSR build
    geom_kernel<<<(N_EDGES + 255) / 256, 256, 0, stream>>>(pos, ei, rbf, dirn);
    zero_i_kernel<<<(N_NODES + 255) / 256, 256, 0, stream>>>(deg, N_NODES);
    hist_kernel<<<(N_EDGES + 255) / 256, 256, 0, stream>>>(dsts, deg);
    prefix_kernel<<<1, 1024, 0, stream>>>(deg, rowptr, cursor);
    scatter_kernel<<<(N_EDGES + 255) / 256, 256, 0, stream>>>(dsts, cursor, eperm);

    init_x_kernel<<<(N_NODES * HIDDEN + 255) / 256, 256, 0, stream>>>(z, embed, x);
    zero_f_kernel<<<(N_NODES * 384 + 255) / 256, 256, 0, stream>>>(vec, N_NODES * 384);

    for (int l = 0; l < 2; l++) {
        // vmix = vec @ Wv[l]   (M = 30000)
        gemm_nn<128, 0><<<(N_NODES * 3 + 63) / 64, 256, 0, stream>>>(
            vec, Wv + (size_t)l * 128 * 128, nullptr, nullptr, vmix, N_NODES * 3);
        // fused edge GEMM
        edge_gemm<<<N_EDGES / 64, 256, 0, stream>>>(rbf, W_rbf + (size_t)l * 32 * 128, x, srcs,
                                                    W1 + (size_t)l * 128 * 128, filt, phi);
        // CSR gather: dxb, vec +=
        gather_kernel<<<N_NODES, 128, 0, stream>>>(rowptr, eperm, srcs, filt, phi, dirn, vmix,
                                                   dxb, vec);
        // x += dxb @ Wo[l]
        gemm_nn<128, 2><<<(N_NODES + 63) / 64, 256, 0, stream>>>(
            dxb, Wo + (size_t)l * 128 * 128, nullptr, x, x, N_NODES);
    }

    // v2 = vec @ Wvec2 (reuse vmix buffer)
    gemm_nn<128, 0><<<(N_NODES * 3 + 63) / 64, 256, 0, stream>>>(vec, Wvec2, nullptr, nullptr,
                                                                 vmix, N_NODES * 3);
    // vnorm (reuse dxb buffer)
    vnorm_kernel<<<(N_NODES * HIDDEN + 255) / 256, 256, 0, stream>>>(vmix, dxb);
    // a = silu(x @ W_a[:128] + b_a + vnorm @ W_a[128:])
    gemm_nn<128, 1><<<(N_NODES + 63) / 64, 256, 0, stream>>>(x, W_a, b_a, nullptr, tmpa, N_NODES);
    gemm_nn<128, 6><<<(N_NODES + 63) / 64, 256, 0, stream>>>(dxb, W_a + 128 * 128, nullptr, tmpa,
                                                             abuf, N_NODES);

    zero_f_kernel<<<(N_GRAPHS * (LATENT + 1) + 255) / 256, 256, 0, stream>>>(
        pooled, N_GRAPHS * (LATENT + 1));
    out_pool_kernel<<<N_NODES, 128, 0, stream>>>(abuf, W_b, b_b, batch, pooled);
    finalize_kernel<<<(N_GRAPHS * (LATENT + 1) + 255) / 256, 256, 0, stream>>>(pooled, out);
}